// Round 1
// baseline (483.272 us; speedup 1.0000x reference)
//
#include <hip/hip_runtime.h>
#include <stdint.h>

#define SEQ 2048
#define NB 4
#define NHD 16
#define HD 64
#define EMB 1024

typedef unsigned short u16;
typedef unsigned int u32;
typedef unsigned long long u64;
typedef __bf16 bf16x8 __attribute__((ext_vector_type(8)));
typedef float f32x4 __attribute__((ext_vector_type(4)));

__device__ __forceinline__ u16 f2bf(float f) {
    u32 u = __builtin_bit_cast(u32, f);
    u32 r = u + 0x7FFFu + ((u >> 16) & 1u);   // RNE
    return (u16)(r >> 16);
}

__device__ __forceinline__ void gld16(const void* g, void* l) {
    __builtin_amdgcn_global_load_lds(
        (const __attribute__((address_space(1))) u32*)g,
        (__attribute__((address_space(3))) u32*)l, 16, 0, 0);
}

// ---------------- prep: Q (scaled 1/32) and K -> bf16 [n][h][s][d] ----------------
__global__ void prep_qk(const float* __restrict__ q, const float* __restrict__ k,
                        u16* __restrict__ qb, u16* __restrict__ kb) {
    int tid = blockIdx.x * 256 + threadIdx.x;   // N*S*H*16 threads
    int unit = tid >> 4;                        // (n,s,h)
    int dq = (tid & 15) << 2;
    int h = unit & (NHD - 1);
    int ns = unit >> 4;                         // n*S+s
    int n = ns >> 11, s = ns & (SEQ - 1);
    size_t src = (size_t)ns * EMB + h * HD + dq;
    float4 qv = *(const float4*)(q + src);
    float4 kv = *(const float4*)(k + src);
    size_t dst = ((size_t)(n * NHD + h) * SEQ + s) * HD + dq;
    ushort4 qo, ko;
    qo.x = f2bf(qv.x * 0.03125f); qo.y = f2bf(qv.y * 0.03125f);
    qo.z = f2bf(qv.z * 0.03125f); qo.w = f2bf(qv.w * 0.03125f);
    ko.x = f2bf(kv.x); ko.y = f2bf(kv.y); ko.z = f2bf(kv.z); ko.w = f2bf(kv.w);
    *(ushort4*)(qb + dst) = qo;
    *(ushort4*)(kb + dst) = ko;
}

// ---------------- prep: V -> bf16 transposed [n][h][d][s] ----------------
__global__ void prep_v(const float* __restrict__ v, u16* __restrict__ vt) {
    __shared__ float t[64][65];
    int s0 = blockIdx.x << 6, h = blockIdx.y, n = blockIdx.z;
    int tid = threadIdx.x;
    int c = (tid & 15) << 2;
    int r0 = tid >> 4;
#pragma unroll
    for (int it = 0; it < 4; it++) {
        int r = r0 + (it << 4);
        float4 val = *(const float4*)(v + ((size_t)n * SEQ + s0 + r) * EMB + h * HD + c);
        t[c][r] = val.x; t[c + 1][r] = val.y; t[c + 2][r] = val.z; t[c + 3][r] = val.w;
    }
    __syncthreads();
    int d = tid >> 2, so = (tid & 3) << 4;
    size_t dst = ((size_t)(n * NHD + h) * HD + d) * SEQ + s0 + so;
#pragma unroll
    for (int j = 0; j < 4; j++) {
        ushort4 o;
        o.x = f2bf(t[d][so + 4 * j + 0]); o.y = f2bf(t[d][so + 4 * j + 1]);
        o.z = f2bf(t[d][so + 4 * j + 2]); o.w = f2bf(t[d][so + 4 * j + 3]);
        *(ushort4*)(vt + dst + 4 * j) = o;
    }
}

// ---------------- prep: mask int32 -> bitmask u64 words via ballot ----------------
__global__ void prep_mask(const int* __restrict__ m, u64* __restrict__ mb) {
    int gw = (blockIdx.x * 256 + threadIdx.x) >> 6;   // global wave id (4096 waves)
    int lane = threadIdx.x & 63;
    for (int i = 0; i < 64; i++) {
        size_t widx = (size_t)gw * 64 + i;            // word index, N*S*32 total
        int v = m[widx * 64 + lane];
        u64 b = __ballot(v != 0);
        if (lane == 0) mb[widx] = b;
    }
}

// ---------------- prep: W -> bf16 ----------------
__global__ void prep_w(const float* __restrict__ w, u16* __restrict__ wb) {
    int tid = blockIdx.x * 256 + threadIdx.x;
    float4 v = *(const float4*)(w + (size_t)tid * 4);
    ushort4 o;
    o.x = f2bf(v.x); o.y = f2bf(v.y); o.z = f2bf(v.z); o.w = f2bf(v.w);
    *(ushort4*)(wb + (size_t)tid * 4) = o;
}

// ---------------- flash attention ----------------
// grid (S/64, H, N), 4 waves; wave owns 16 q rows. K-tile = 64, double-buffered.
__global__ __launch_bounds__(256, 2) void attn_k(
    const u16* __restrict__ qb, const u16* __restrict__ kb,
    const u16* __restrict__ vt, const u64* __restrict__ mbits,
    u16* __restrict__ ao)
{
    __shared__ __align__(16) u16 lds_k[2][64 * 64];
    __shared__ __align__(16) u16 lds_v[2][64 * 64];
    __shared__ __align__(16) u16 lds_p[4][16 * 64];
    const int tid = threadIdx.x;
    const int wave = tid >> 6, lane = tid & 63;
    const int g = lane >> 4, c16 = lane & 15;
    const int n = blockIdx.z, h = blockIdx.y;
    const int qw = (blockIdx.x << 6) + (wave << 4);
    const size_t nh = (size_t)(n * NHD + h);
    const u16* Qp = qb + nh * SEQ * HD;
    const u16* Kp = kb + nh * SEQ * HD;
    const u16* Vp = vt + nh * HD * SEQ;

    // Q fragments (row = c16, k = 8g [+32])
    bf16x8 qa0 = *(const bf16x8*)(Qp + (size_t)(qw + c16) * HD + 8 * g);
    bf16x8 qa1 = *(const bf16x8*)(Qp + (size_t)(qw + c16) * HD + 8 * g + 32);

    f32x4 o[4];
    float m_r[4], l_r[4];
#pragma unroll
    for (int i = 0; i < 4; i++) { o[i] = (f32x4){0.f, 0.f, 0.f, 0.f}; m_r[i] = -INFINITY; l_r[i] = 0.f; }

    const u64* mrow = mbits + ((size_t)n * SEQ + qw + 4 * g) * (SEQ / 64);

    auto STAGE = [&](int buf, int kt) {
        int k0 = kt << 6;
#pragma unroll
        for (int i = 0; i < 2; i++) {
            int off = (i << 8) + tid;                 // 16B-chunk index 0..511
            int row = off >> 3;
            int sch = (off & 7) ^ (row & 7);          // pre-swizzled source chunk
            int ldso = ((i << 8) + (wave << 6)) << 3; // wave-uniform LDS base (elems)
            gld16(Kp + (size_t)(k0 + row) * HD + (sch << 3), &lds_k[buf][ldso]);
            gld16(Vp + (size_t)row * SEQ + k0 + (sch << 3), &lds_v[buf][ldso]);
        }
    };

    auto COMPUTE = [&](int buf, int kt) {
        u64 mw[4];
#pragma unroll
        for (int r = 0; r < 4; r++) mw[r] = mrow[r * (SEQ / 64) + kt];
        f32x4 s[4];
#pragma unroll
        for (int t = 0; t < 4; t++) {
            int kc = (t << 4) + c16;
            int sw = (kc & 7) << 3;
            bf16x8 kf0 = *(const bf16x8*)&lds_k[buf][kc * 64 + ((8 * g) ^ sw)];
            bf16x8 kf1 = *(const bf16x8*)&lds_k[buf][kc * 64 + ((8 * g + 32) ^ sw)];
            f32x4 acc = (f32x4){0.f, 0.f, 0.f, 0.f};
            acc = __builtin_amdgcn_mfma_f32_16x16x32_bf16(qa0, kf0, acc, 0, 0, 0);
            acc = __builtin_amdgcn_mfma_f32_16x16x32_bf16(qa1, kf1, acc, 0, 0, 0);
#pragma unroll
            for (int r = 0; r < 4; r++) {
                float val = acc[r];
                if (!((mw[r] >> kc) & 1ull)) val = -1e20f;
                s[t][r] = val;
            }
        }
        float mnew[4], sc[4], ladd[4];
#pragma unroll
        for (int r = 0; r < 4; r++) {
            float v = fmaxf(fmaxf(s[0][r], s[1][r]), fmaxf(s[2][r], s[3][r]));
#pragma unroll
            for (int msk = 1; msk < 16; msk <<= 1) v = fmaxf(v, __shfl_xor(v, msk));
            mnew[r] = fmaxf(m_r[r], v);
            sc[r] = __expf(m_r[r] - mnew[r]);
            ladd[r] = 0.f;
        }
#pragma unroll
        for (int t = 0; t < 4; t++)
#pragma unroll
            for (int r = 0; r < 4; r++) {
                float p = __expf(s[t][r] - mnew[r]);
                s[t][r] = p;
                ladd[r] += p;
            }
#pragma unroll
        for (int r = 0; r < 4; r++) {
#pragma unroll
            for (int msk = 1; msk < 16; msk <<= 1) ladd[r] += __shfl_xor(ladd[r], msk);
            l_r[r] = l_r[r] * sc[r] + ladd[r];
            m_r[r] = mnew[r];
        }
#pragma unroll
        for (int dt = 0; dt < 4; dt++)
#pragma unroll
            for (int r = 0; r < 4; r++) o[dt][r] *= sc[r];
        // P -> per-wave swizzled LDS (re-fragment for PV)
#pragma unroll
        for (int t = 0; t < 4; t++)
#pragma unroll
            for (int r = 0; r < 4; r++) {
                int row = 4 * g + r;
                int col = (t << 4) + c16;
                lds_p[wave][row * 64 + (col ^ ((row & 7) << 3))] = f2bf(s[t][r]);
            }
#pragma unroll
        for (int c = 0; c < 2; c++) {
            bf16x8 pa = *(const bf16x8*)&lds_p[wave][c16 * 64 + ((8 * g + 32 * c) ^ ((c16 & 7) << 3))];
#pragma unroll
            for (int dt = 0; dt < 4; dt++) {
                int dr = (dt << 4) + c16;
                bf16x8 vf = *(const bf16x8*)&lds_v[buf][dr * 64 + ((8 * g + 32 * c) ^ ((dr & 7) << 3))];
                o[dt] = __builtin_amdgcn_mfma_f32_16x16x32_bf16(pa, vf, o[dt], 0, 0, 0);
            }
        }
    };

    STAGE(0, 0);
    __syncthreads();
    for (int kt = 0; kt < SEQ / 64; kt++) {
        int buf = kt & 1;
        if (kt + 1 < SEQ / 64) STAGE(buf ^ 1, kt + 1);
        COMPUTE(buf, kt);
        __syncthreads();
    }

#pragma unroll
    for (int dt = 0; dt < 4; dt++)
#pragma unroll
        for (int r = 0; r < 4; r++) {
            float val = o[dt][r] / l_r[r];
            int q = qw + 4 * g + r;
            int e = h * HD + (dt << 4) + c16;
            ao[((size_t)n * SEQ + q) * EMB + e] = f2bf(val);
        }
}

// ---------------- output projection: out[M=8192][1024] = A[M][1024] @ W[1024][1024]^T + b ----------------
// 128x128 tile, BK=64, 4 waves 2x2, 2-phase double-buffered.
__global__ __launch_bounds__(256, 2) void proj_k(
    const u16* __restrict__ a, const u16* __restrict__ w,
    const float* __restrict__ bias, float* __restrict__ out)
{
    __shared__ __align__(16) u16 lds_a[2][128 * 64];
    __shared__ __align__(16) u16 lds_b[2][128 * 64];
    const int tid = threadIdx.x;
    const int wave = tid >> 6, lane = tid & 63;
    const int g = lane >> 4, c16 = lane & 15;
    const int m0 = blockIdx.y << 7, n0 = blockIdx.x << 7;
    const int wm = wave >> 1, wn = wave & 1;
    f32x4 acc[4][4];
#pragma unroll
    for (int i = 0; i < 4; i++)
#pragma unroll
        for (int j = 0; j < 4; j++) acc[i][j] = (f32x4){0.f, 0.f, 0.f, 0.f};

    auto STAGE = [&](int buf, int k0) {
#pragma unroll
        for (int i = 0; i < 4; i++) {
            int off = (i << 8) + tid;
            int row = off >> 3;
            int sch = (off & 7) ^ (row & 7);
            int ldso = ((i << 8) + (wave << 6)) << 3;
            gld16(a + (size_t)(m0 + row) * EMB + k0 + (sch << 3), &lds_a[buf][ldso]);
            gld16(w + (size_t)(n0 + row) * EMB + k0 + (sch << 3), &lds_b[buf][ldso]);
        }
    };

    auto COMP = [&](int buf) {
#pragma unroll
        for (int c = 0; c < 2; c++) {
            bf16x8 af[4], bfr[4];
#pragma unroll
            for (int mt = 0; mt < 4; mt++) {
                int row = (wm << 6) + (mt << 4) + c16;
                af[mt] = *(const bf16x8*)&lds_a[buf][row * 64 + ((8 * g + 32 * c) ^ ((row & 7) << 3))];
            }
#pragma unroll
            for (int nt = 0; nt < 4; nt++) {
                int row = (wn << 6) + (nt << 4) + c16;
                bfr[nt] = *(const bf16x8*)&lds_b[buf][row * 64 + ((8 * g + 32 * c) ^ ((row & 7) << 3))];
            }
#pragma unroll
            for (int mt = 0; mt < 4; mt++)
#pragma unroll
                for (int nt = 0; nt < 4; nt++)
                    acc[mt][nt] = __builtin_amdgcn_mfma_f32_16x16x32_bf16(af[mt], bfr[nt], acc[mt][nt], 0, 0, 0);
        }
    };

    STAGE(0, 0);
    __syncthreads();
    for (int ki = 0; ki < EMB / 64; ki++) {
        int buf = ki & 1;
        if (ki + 1 < EMB / 64) STAGE(buf ^ 1, (ki + 1) << 6);
        COMP(buf);
        __syncthreads();
    }

#pragma unroll
    for (int nt = 0; nt < 4; nt++) {
        int col = n0 + (wn << 6) + (nt << 4) + c16;
        float bv = bias[col];
#pragma unroll
        for (int mt = 0; mt < 4; mt++) {
#pragma unroll
            for (int r = 0; r < 4; r++) {
                int row = m0 + (wm << 6) + (mt << 4) + 4 * g + r;
                out[(size_t)row * EMB + col] = acc[mt][nt][r] + bv;
            }
        }
    }
}

extern "C" void kernel_launch(void* const* d_in, const int* in_sizes, int n_in,
                              void* d_out, int out_size, void* d_ws, size_t ws_size,
                              hipStream_t stream) {
    const float* V = (const float*)d_in[0];
    const float* K = (const float*)d_in[1];
    const float* Q = (const float*)d_in[2];
    const int* M = (const int*)d_in[3];
    const float* W = (const float*)d_in[4];
    const float* B = (const float*)d_in[5];
    float* out = (float*)d_out;

    char* ws = (char*)d_ws;
    u16* qb = (u16*)(ws);                       // 16 MB  [n][h][s][d] bf16, pre-scaled 1/32
    u16* kb = (u16*)(ws + ((size_t)16 << 20));  // 16 MB
    u16* vt = (u16*)(ws + ((size_t)32 << 20));  // 16 MB  [n][h][d][s]
    u64* mb = (u64*)(ws + ((size_t)48 << 20));  //  2 MB  bitmask
    u16* wb = (u16*)(ws + ((size_t)50 << 20));  //  2 MB  W bf16
    u16* ao = (u16*)(ws + ((size_t)52 << 20));  // 16 MB  attn out bf16 [n][q][e]

    prep_qk<<<8192, 256, 0, stream>>>(Q, K, qb, kb);
    prep_v<<<dim3(SEQ / 64, NHD, NB), 256, 0, stream>>>(V, vt);
    prep_mask<<<1024, 256, 0, stream>>>(M, mb);
    prep_w<<<1024, 256, 0, stream>>>(W, wb);
    attn_k<<<dim3(SEQ / 64, NHD, NB), 256, 0, stream>>>(qb, kb, vt, mb, ao);
    proj_k<<<dim3(EMB / 128, (NB * SEQ) / 128), 256, 0, stream>>>(ao, wb, B, out);
}

// Round 3
// 397.319 us; speedup vs baseline: 1.2163x; 1.2163x over previous
//
#include <hip/hip_runtime.h>
#include <stdint.h>

#define SEQ 2048
#define NB 4
#define NHD 16
#define HD 64
#define EMB 1024

typedef unsigned short u16;
typedef unsigned int u32;
typedef unsigned long long u64;
typedef __bf16 bf16x8 __attribute__((ext_vector_type(8)));
typedef float f32x4 __attribute__((ext_vector_type(4)));

__device__ __forceinline__ u16 f2bf(float f) {
    u32 u = __builtin_bit_cast(u32, f);
    u32 r = u + 0x7FFFu + ((u >> 16) & 1u);   // RNE
    return (u16)(r >> 16);
}

__device__ __forceinline__ float exp2_hw(float x) {
    float r;
    asm("v_exp_f32 %0, %1" : "=v"(r) : "v"(x));
    return r;
}

__device__ __forceinline__ u32 cvtpk_bf16(float lo, float hi) {
    u32 r;
    asm("v_cvt_pk_bf16_f32 %0, %1, %2" : "=v"(r) : "v"(lo), "v"(hi));
    return r;
}

__device__ __forceinline__ void gld16(const void* g, void* l) {
    __builtin_amdgcn_global_load_lds(
        (const __attribute__((address_space(1))) u32*)g,
        (__attribute__((address_space(3))) u32*)l, 16, 0, 0);
}

// ---------------- prep: Q (scaled log2e/32) and K -> bf16 [n][h][s][d] ----------------
__global__ void prep_qk(const float* __restrict__ q, const float* __restrict__ k,
                        u16* __restrict__ qb, u16* __restrict__ kb) {
    int tid = blockIdx.x * 256 + threadIdx.x;   // N*S*H*16 threads
    int unit = tid >> 4;                        // (n,s,h)
    int dq = (tid & 15) << 2;
    int h = unit & (NHD - 1);
    int ns = unit >> 4;                         // n*S+s
    int n = ns >> 11, s = ns & (SEQ - 1);
    size_t src = (size_t)ns * EMB + h * HD + dq;
    float4 qv = *(const float4*)(q + src);
    float4 kv = *(const float4*)(k + src);
    size_t dst = ((size_t)(n * NHD + h) * SEQ + s) * HD + dq;
    const float QS = 0.04508422f;               // (1/32) * log2(e): S in exp2 domain
    ushort4 qo, ko;
    qo.x = f2bf(qv.x * QS); qo.y = f2bf(qv.y * QS);
    qo.z = f2bf(qv.z * QS); qo.w = f2bf(qv.w * QS);
    ko.x = f2bf(kv.x); ko.y = f2bf(kv.y); ko.z = f2bf(kv.z); ko.w = f2bf(kv.w);
    *(ushort4*)(qb + dst) = qo;
    *(ushort4*)(kb + dst) = ko;
}

// ---------------- prep: V -> bf16 transposed [n][h][d][s] ----------------
__global__ void prep_v(const float* __restrict__ v, u16* __restrict__ vt) {
    __shared__ float t[64][65];
    int s0 = blockIdx.x << 6, h = blockIdx.y, n = blockIdx.z;
    int tid = threadIdx.x;
    int c = (tid & 15) << 2;
    int r0 = tid >> 4;
#pragma unroll
    for (int it = 0; it < 4; it++) {
        int r = r0 + (it << 4);
        float4 val = *(const float4*)(v + ((size_t)n * SEQ + s0 + r) * EMB + h * HD + c);
        t[c][r] = val.x; t[c + 1][r] = val.y; t[c + 2][r] = val.z; t[c + 3][r] = val.w;
    }
    __syncthreads();
    int d = tid >> 2, so = (tid & 3) << 4;
    size_t dst = ((size_t)(n * NHD + h) * HD + d) * SEQ + s0 + so;
#pragma unroll
    for (int j = 0; j < 4; j++) {
        ushort4 o;
        o.x = f2bf(t[d][so + 4 * j + 0]); o.y = f2bf(t[d][so + 4 * j + 1]);
        o.z = f2bf(t[d][so + 4 * j + 2]); o.w = f2bf(t[d][so + 4 * j + 3]);
        *(ushort4*)(vt + dst + 4 * j) = o;
    }
}

// ---------------- prep: W -> bf16 ----------------
__global__ void prep_w(const float* __restrict__ w, u16* __restrict__ wb) {
    int tid = blockIdx.x * 256 + threadIdx.x;
    float4 v = *(const float4*)(w + (size_t)tid * 4);
    ushort4 o;
    o.x = f2bf(v.x); o.y = f2bf(v.y); o.z = f2bf(v.z); o.w = f2bf(v.w);
    *(ushort4*)(wb + (size_t)tid * 4) = o;
}

// ---------------- flash attention (swapped-operand: lane owns one q-row) ----------------
// 1-D grid 2048 blocks (T1 chunked XCD swizzle), 4 waves; wave owns 16 q rows. K-tile=64.
__global__ __launch_bounds__(256, 4) void attn_k(
    const u16* __restrict__ qb, const u16* __restrict__ kb,
    const u16* __restrict__ vt, const int* __restrict__ mask,
    u16* __restrict__ ao)
{
    __shared__ __align__(16) u16 lds_k[2][64 * 64];
    __shared__ __align__(16) u16 lds_v[2][64 * 64];
    __shared__ __align__(16) u16 lds_p[4][16 * 64];
    const int tid = threadIdx.x;
    const int wave = tid >> 6, lane = tid & 63;
    const int g = lane >> 4, c16 = lane & 15;
    // T1 chunked swizzle: XCD x gets contiguous work chunk (K/V/mask L2-resident)
    const int bid = blockIdx.x;
    const int swz = (bid & 7) * 256 + (bid >> 3);
    const int n = swz >> 9, h = (swz >> 5) & 15, qt = swz & 31;
    const int qw = (qt << 6) + (wave << 4);
    const size_t nh = (size_t)(n * NHD + h);
    const u16* Qp = qb + nh * SEQ * HD;
    const u16* Kp = kb + nh * SEQ * HD;
    const u16* Vp = vt + nh * HD * SEQ;
    const int* mrow = mask + ((size_t)n * SEQ + qw + c16) * SEQ;

    // Q fragments: B-operand, lane holds col(q)=c16, contraction d = 8g.. (+32)
    bf16x8 qa0 = *(const bf16x8*)(Qp + (size_t)(qw + c16) * HD + 8 * g);
    bf16x8 qa1 = *(const bf16x8*)(Qp + (size_t)(qw + c16) * HD + 8 * g + 32);

    f32x4 o[4];
#pragma unroll
    for (int i = 0; i < 4; i++) o[i] = (f32x4){0.f, 0.f, 0.f, 0.f};
    float m_r = -INFINITY, l_r = 0.f;

    auto STAGE = [&](int buf, int kt) {
        int k0 = kt << 6;
#pragma unroll
        for (int i = 0; i < 2; i++) {
            int off = (i << 8) + tid;                 // 16B-chunk index 0..511
            int row = off >> 3;
            int sch = (off & 7) ^ (row & 7);          // pre-swizzled source chunk
            int ldso = ((i << 8) + (wave << 6)) << 3; // wave-uniform LDS base (elems)
            gld16(Kp + (size_t)(k0 + row) * HD + (sch << 3), &lds_k[buf][ldso]);
            gld16(Vp + (size_t)row * SEQ + k0 + (sch << 3), &lds_v[buf][ldso]);
        }
    };

    auto COMPUTE = [&](int buf, int kt) {
        // mask bias as MFMA C-init: S^T[k=16t+4g+r][q=c16]
        f32x4 s[4];
#pragma unroll
        for (int t = 0; t < 4; t++) {
            int4 mv = *(const int4*)(mrow + (kt << 6) + (t << 4) + (g << 2));
            s[t][0] = fmaf((float)mv.x, 1e20f, -1e20f);
            s[t][1] = fmaf((float)mv.y, 1e20f, -1e20f);
            s[t][2] = fmaf((float)mv.z, 1e20f, -1e20f);
            s[t][3] = fmaf((float)mv.w, 1e20f, -1e20f);
        }
#pragma unroll
        for (int t = 0; t < 4; t++) {
            int kc = (t << 4) + c16;
            int sw = (kc & 7) << 3;
            bf16x8 kf0 = *(const bf16x8*)&lds_k[buf][kc * 64 + ((8 * g) ^ sw)];
            bf16x8 kf1 = *(const bf16x8*)&lds_k[buf][kc * 64 + ((8 * g + 32) ^ sw)];
            s[t] = __builtin_amdgcn_mfma_f32_16x16x32_bf16(kf0, qa0, s[t], 0, 0, 0);
            s[t] = __builtin_amdgcn_mfma_f32_16x16x32_bf16(kf1, qa1, s[t], 0, 0, 0);
        }
        // per-lane row max over 16 values + cross-g reduce (2 shfl)
        float pmax = fmaxf(fmaxf(fmaxf(s[0][0], s[0][1]), fmaxf(s[0][2], s[0][3])),
                           fmaxf(fmaxf(s[1][0], s[1][1]), fmaxf(s[1][2], s[1][3])));
        pmax = fmaxf(pmax, fmaxf(fmaxf(fmaxf(s[2][0], s[2][1]), fmaxf(s[2][2], s[2][3])),
                                 fmaxf(fmaxf(s[3][0], s[3][1]), fmaxf(s[3][2], s[3][3]))));
        pmax = fmaxf(pmax, __shfl_xor(pmax, 16));
        pmax = fmaxf(pmax, __shfl_xor(pmax, 32));
        // defer-max (T13): rescale only when max grew past threshold (exp2 domain, THR=8)
        if (__ballot(pmax > m_r + 8.f)) {
            float mnew = fmaxf(m_r, pmax);
            float sc = exp2_hw(m_r - mnew);
            m_r = mnew;
            l_r *= sc;
#pragma unroll
            for (int dt = 0; dt < 4; dt++) o[dt] *= sc;
        }
        // P = exp2(S - m), pack to bf16 pairs
        float ladd = 0.f;
        u32 pk[4][2];
#pragma unroll
        for (int t = 0; t < 4; t++) {
            float p0 = exp2_hw(s[t][0] - m_r);
            float p1 = exp2_hw(s[t][1] - m_r);
            float p2 = exp2_hw(s[t][2] - m_r);
            float p3 = exp2_hw(s[t][3] - m_r);
            ladd += (p0 + p1) + (p2 + p3);
            pk[t][0] = cvtpk_bf16(p0, p1);
            pk[t][1] = cvtpk_bf16(p2, p3);
        }
        ladd += __shfl_xor(ladd, 16);
        ladd += __shfl_xor(ladd, 32);
        l_r += ladd;
        // P[q=c16][k] -> per-wave swizzled LDS (cross-g exchange), 4x ds_write_b64
        char* pbase = (char*)&lds_p[wave][0];
        int swp = (c16 & 7) << 4;
#pragma unroll
        for (int t = 0; t < 4; t++) {
            u64 w2 = ((u64)pk[t][1] << 32) | pk[t][0];
            *(u64*)(pbase + ((c16 * 128 + 32 * t + 8 * g) ^ swp)) = w2;
        }
        // PV (swapped): O^T[d][q=c16] += V^T-frag(A) x P-frag(B)
        bf16x8 pa0 = *(const bf16x8*)(pbase + ((c16 * 128 + 16 * g) ^ swp));
        bf16x8 pa1 = *(const bf16x8*)(pbase + ((c16 * 128 + 64 + 16 * g) ^ swp));
#pragma unroll
        for (int dt = 0; dt < 4; dt++) {
            int dr = (dt << 4) + c16;
            int swv = (dr & 7) << 3;
            bf16x8 vf0 = *(const bf16x8*)&lds_v[buf][dr * 64 + ((8 * g) ^ swv)];
            bf16x8 vf1 = *(const bf16x8*)&lds_v[buf][dr * 64 + ((8 * g + 32) ^ swv)];
            o[dt] = __builtin_amdgcn_mfma_f32_16x16x32_bf16(vf0, pa0, o[dt], 0, 0, 0);
            o[dt] = __builtin_amdgcn_mfma_f32_16x16x32_bf16(vf1, pa1, o[dt], 0, 0, 0);
        }
    };

    STAGE(0, 0);
    __syncthreads();
    for (int kt = 0; kt < SEQ / 64; kt++) {
        int buf = kt & 1;
        if (kt + 1 < SEQ / 64) STAGE(buf ^ 1, kt + 1);
        COMPUTE(buf, kt);
        __syncthreads();
    }

    // epilogue: out[q=c16][d=16dt+4g+r] = o/l  (4x 8B stores)
    float inv = 1.f / l_r;
    size_t obase = ((size_t)n * SEQ + qw + c16) * EMB + h * HD;
#pragma unroll
    for (int dt = 0; dt < 4; dt++) {
        u32 w0 = cvtpk_bf16(o[dt][0] * inv, o[dt][1] * inv);
        u32 w1 = cvtpk_bf16(o[dt][2] * inv, o[dt][3] * inv);
        u64 w2 = ((u64)w1 << 32) | w0;
        *(u64*)(ao + obase + (dt << 4) + (g << 2)) = w2;
    }
}

// ---------------- output projection: out[M=8192][1024] = A[M][1024] @ W[1024][1024]^T + b ----------------
__global__ __launch_bounds__(256, 2) void proj_k(
    const u16* __restrict__ a, const u16* __restrict__ w,
    const float* __restrict__ bias, float* __restrict__ out)
{
    __shared__ __align__(16) u16 lds_a[2][128 * 64];
    __shared__ __align__(16) u16 lds_b[2][128 * 64];
    const int tid = threadIdx.x;
    const int wave = tid >> 6, lane = tid & 63;
    const int g = lane >> 4, c16 = lane & 15;
    const int m0 = blockIdx.y << 7, n0 = blockIdx.x << 7;
    const int wm = wave >> 1, wn = wave & 1;
    f32x4 acc[4][4];
#pragma unroll
    for (int i = 0; i < 4; i++)
#pragma unroll
        for (int j = 0; j < 4; j++) acc[i][j] = (f32x4){0.f, 0.f, 0.f, 0.f};

    auto STAGE = [&](int buf, int k0) {
#pragma unroll
        for (int i = 0; i < 4; i++) {
            int off = (i << 8) + tid;
            int row = off >> 3;
            int sch = (off & 7) ^ (row & 7);
            int ldso = ((i << 8) + (wave << 6)) << 3;
            gld16(a + (size_t)(m0 + row) * EMB + k0 + (sch << 3), &lds_a[buf][ldso]);
            gld16(w + (size_t)(n0 + row) * EMB + k0 + (sch << 3), &lds_b[buf][ldso]);
        }
    };

    auto COMP = [&](int buf) {
#pragma unroll
        for (int c = 0; c < 2; c++) {
            bf16x8 af[4], bfr[4];
#pragma unroll
            for (int mt = 0; mt < 4; mt++) {
                int row = (wm << 6) + (mt << 4) + c16;
                af[mt] = *(const bf16x8*)&lds_a[buf][row * 64 + ((8 * g + 32 * c) ^ ((row & 7) << 3))];
            }
#pragma unroll
            for (int nt = 0; nt < 4; nt++) {
                int row = (wn << 6) + (nt << 4) + c16;
                bfr[nt] = *(const bf16x8*)&lds_b[buf][row * 64 + ((8 * g + 32 * c) ^ ((row & 7) << 3))];
            }
#pragma unroll
            for (int mt = 0; mt < 4; mt++)
#pragma unroll
                for (int nt = 0; nt < 4; nt++)
                    acc[mt][nt] = __builtin_amdgcn_mfma_f32_16x16x32_bf16(af[mt], bfr[nt], acc[mt][nt], 0, 0, 0);
        }
    };

    STAGE(0, 0);
    __syncthreads();
    for (int ki = 0; ki < EMB / 64; ki++) {
        int buf = ki & 1;
        if (ki + 1 < EMB / 64) STAGE(buf ^ 1, (ki + 1) << 6);
        COMP(buf);
        __syncthreads();
    }

#pragma unroll
    for (int nt = 0; nt < 4; nt++) {
        int col = n0 + (wn << 6) + (nt << 4) + c16;
        float bv = bias[col];
#pragma unroll
        for (int mt = 0; mt < 4; mt++) {
#pragma unroll
            for (int r = 0; r < 4; r++) {
                int row = m0 + (wm << 6) + (mt << 4) + 4 * g + r;
                out[(size_t)row * EMB + col] = acc[mt][nt][r] + bv;
            }
        }
    }
}

extern "C" void kernel_launch(void* const* d_in, const int* in_sizes, int n_in,
                              void* d_out, int out_size, void* d_ws, size_t ws_size,
                              hipStream_t stream) {
    const float* V = (const float*)d_in[0];
    const float* K = (const float*)d_in[1];
    const float* Q = (const float*)d_in[2];
    const int* M = (const int*)d_in[3];
    const float* W = (const float*)d_in[4];
    const float* B = (const float*)d_in[5];
    float* out = (float*)d_out;

    char* ws = (char*)d_ws;
    u16* qb = (u16*)(ws);                       // 16 MB  [n][h][s][d] bf16, pre-scaled log2e/32
    u16* kb = (u16*)(ws + ((size_t)16 << 20));  // 16 MB
    u16* vt = (u16*)(ws + ((size_t)32 << 20));  // 16 MB  [n][h][d][s]
    u16* wb = (u16*)(ws + ((size_t)48 << 20));  //  2 MB  W bf16
    u16* ao = (u16*)(ws + ((size_t)50 << 20));  // 16 MB  attn out bf16 [n][q][e]

    prep_qk<<<8192, 256, 0, stream>>>(Q, K, qb, kb);
    prep_v<<<dim3(SEQ / 64, NHD, NB), 256, 0, stream>>>(V, vt);
    prep_w<<<1024, 256, 0, stream>>>(W, wb);
    attn_k<<<2048, 256, 0, stream>>>(qb, kb, vt, M, ao);
    proj_k<<<dim3(EMB / 128, (NB * SEQ) / 128), 256, 0, stream>>>(ao, wb, B, out);
}

// Round 5
// 376.687 us; speedup vs baseline: 1.2830x; 1.0548x over previous
//
#include <hip/hip_runtime.h>
#include <stdint.h>

#define SEQ 2048
#define NB 4
#define NHD 16
#define HD 64
#define EMB 1024

typedef unsigned short u16;
typedef unsigned int u32;
typedef unsigned long long u64;
typedef __bf16 bf16x8 __attribute__((ext_vector_type(8)));
typedef float f32x4 __attribute__((ext_vector_type(4)));

__device__ __forceinline__ u16 f2bf(float f) {
    u32 u = __builtin_bit_cast(u32, f);
    u32 r = u + 0x7FFFu + ((u >> 16) & 1u);   // RNE
    return (u16)(r >> 16);
}

__device__ __forceinline__ float exp2_hw(float x) {
    float r;
    asm("v_exp_f32 %0, %1" : "=v"(r) : "v"(x));
    return r;
}

__device__ __forceinline__ u32 cvtpk_bf16(float lo, float hi) {
    u32 r;
    asm("v_cvt_pk_bf16_f32 %0, %1, %2" : "=v"(r) : "v"(lo), "v"(hi));
    return r;
}

__device__ __forceinline__ void gld16(const void* g, void* l) {
    __builtin_amdgcn_global_load_lds(
        (const __attribute__((address_space(1))) u32*)g,
        (__attribute__((address_space(3))) u32*)l, 16, 0, 0);
}

// ---------------- prep: Q (scaled log2e/32) and K -> bf16 [n][h][s][d] ----------------
__global__ void prep_qk(const float* __restrict__ q, const float* __restrict__ k,
                        u16* __restrict__ qb, u16* __restrict__ kb) {
    int tid = blockIdx.x * 256 + threadIdx.x;   // N*S*H*16 threads
    int unit = tid >> 4;                        // (n,s,h)
    int dq = (tid & 15) << 2;
    int h = unit & (NHD - 1);
    int ns = unit >> 4;                         // n*S+s
    int n = ns >> 11, s = ns & (SEQ - 1);
    size_t src = (size_t)ns * EMB + h * HD + dq;
    float4 qv = *(const float4*)(q + src);
    float4 kv = *(const float4*)(k + src);
    size_t dst = ((size_t)(n * NHD + h) * SEQ + s) * HD + dq;
    const float QS = 0.04508422f;               // (1/32) * log2(e): S in exp2 domain
    ushort4 qo, ko;
    qo.x = f2bf(qv.x * QS); qo.y = f2bf(qv.y * QS);
    qo.z = f2bf(qv.z * QS); qo.w = f2bf(qv.w * QS);
    ko.x = f2bf(kv.x); ko.y = f2bf(kv.y); ko.z = f2bf(kv.z); ko.w = f2bf(kv.w);
    *(ushort4*)(qb + dst) = qo;
    *(ushort4*)(kb + dst) = ko;
}

// ---------------- prep: V -> bf16 transposed [n][h][d][s] ----------------
__global__ void prep_v(const float* __restrict__ v, u16* __restrict__ vt) {
    __shared__ float t[64][65];
    int s0 = blockIdx.x << 6, h = blockIdx.y, n = blockIdx.z;
    int tid = threadIdx.x;
    int c = (tid & 15) << 2;
    int r0 = tid >> 4;
#pragma unroll
    for (int it = 0; it < 4; it++) {
        int r = r0 + (it << 4);
        float4 val = *(const float4*)(v + ((size_t)n * SEQ + s0 + r) * EMB + h * HD + c);
        t[c][r] = val.x; t[c + 1][r] = val.y; t[c + 2][r] = val.z; t[c + 3][r] = val.w;
    }
    __syncthreads();
    int d = tid >> 2, so = (tid & 3) << 4;
    size_t dst = ((size_t)(n * NHD + h) * HD + d) * SEQ + s0 + so;
#pragma unroll
    for (int j = 0; j < 4; j++) {
        ushort4 o;
        o.x = f2bf(t[d][so + 4 * j + 0]); o.y = f2bf(t[d][so + 4 * j + 1]);
        o.z = f2bf(t[d][so + 4 * j + 2]); o.w = f2bf(t[d][so + 4 * j + 3]);
        *(ushort4*)(vt + dst + 4 * j) = o;
    }
}

// ---------------- prep: mask int32 -> permuted-bit u64 words via ballot ----------------
// bit j (j = g*16 + t*4 + r) holds mask element k = t*16 + g*4 + r of the word's
// 64-element span -> attn lane (g) reads its 16 bits as one contiguous field.
__global__ void prep_mask(const int* __restrict__ m, u64* __restrict__ mb) {
    int gw = (blockIdx.x * 256 + threadIdx.x) >> 6;   // global wave id (4096 waves)
    int lane = threadIdx.x & 63;
    int src = ((lane & 12) << 2) | ((lane & 48) >> 2) | (lane & 3);
    for (int i = 0; i < 64; i++) {
        size_t widx = (size_t)gw * 64 + i;            // word index, N*S*32 total
        int v = m[widx * 64 + src];
        u64 b = __ballot(v != 0);
        if (lane == 0) mb[widx] = b;
    }
}

// ---------------- prep: W -> bf16 ----------------
__global__ void prep_w(const float* __restrict__ w, u16* __restrict__ wb) {
    int tid = blockIdx.x * 256 + threadIdx.x;
    float4 v = *(const float4*)(w + (size_t)tid * 4);
    ushort4 o;
    o.x = f2bf(v.x); o.y = f2bf(v.y); o.z = f2bf(v.z); o.w = f2bf(v.w);
    *(ushort4*)(wb + (size_t)tid * 4) = o;
}

// ---------------- flash attention (swapped-operand, defer-max online softmax) ----------------
// 1-D grid 2048 blocks (T1 chunked XCD swizzle), 4 waves; wave owns 16 q rows. K-tile=64.
__global__ __launch_bounds__(256, 4) void attn_k(
    const u16* __restrict__ qb, const u16* __restrict__ kb,
    const u16* __restrict__ vt, const u64* __restrict__ mbits,
    u16* __restrict__ ao)
{
    __shared__ __align__(16) u16 lds_k[2][64 * 64];
    __shared__ __align__(16) u16 lds_v[2][64 * 64];
    __shared__ __align__(16) u16 lds_p[4][16 * 64];
    const int tid = threadIdx.x;
    const int wave = tid >> 6, lane = tid & 63;
    const int g = lane >> 4, c16 = lane & 15;
    // T1 chunked swizzle: XCD x gets contiguous work chunk (K/V/mask L2-resident)
    const int bid = blockIdx.x;
    const int swz = (bid & 7) * 256 + (bid >> 3);
    const int n = swz >> 9, h = (swz >> 5) & 15, qt = swz & 31;
    const int qw = (qt << 6) + (wave << 4);
    const size_t nh = (size_t)(n * NHD + h);
    const u16* Qp = qb + nh * SEQ * HD;
    const u16* Kp = kb + nh * SEQ * HD;
    const u16* Vp = vt + nh * HD * SEQ;
    const u64* mrow = mbits + ((size_t)n * SEQ + qw + c16) * (SEQ / 64);

    // Q fragments: B-operand, lane holds col(q)=c16, contraction d = 8g.. (+32)
    bf16x8 qa0 = *(const bf16x8*)(Qp + (size_t)(qw + c16) * HD + 8 * g);
    bf16x8 qa1 = *(const bf16x8*)(Qp + (size_t)(qw + c16) * HD + 8 * g + 32);

    f32x4 o[4];
#pragma unroll
    for (int i = 0; i < 4; i++) o[i] = (f32x4){0.f, 0.f, 0.f, 0.f};
    float m_r = -INFINITY, l_r = 0.f;

    auto STAGE = [&](int buf, int kt) {
        int k0 = kt << 6;
#pragma unroll
        for (int i = 0; i < 2; i++) {
            int off = (i << 8) + tid;                 // 16B-chunk index 0..511
            int row = off >> 3;
            int sch = (off & 7) ^ (row & 7);          // pre-swizzled source chunk
            int ldso = ((i << 8) + (wave << 6)) << 3; // wave-uniform LDS base (elems)
            gld16(Kp + (size_t)(k0 + row) * HD + (sch << 3), &lds_k[buf][ldso]);
            gld16(Vp + (size_t)row * SEQ + k0 + (sch << 3), &lds_v[buf][ldso]);
        }
    };

    auto COMPUTE = [&](int buf, int kt) {
        // mask bias as MFMA C-init from permuted bitfield: lane's 16 bits contiguous
        u64 mw_cur = mrow[kt];
        u32 mloc = (u32)(mw_cur >> (g << 4)) & 0xFFFFu;
        f32x4 s[4];
#pragma unroll
        for (int t = 0; t < 4; t++)
#pragma unroll
            for (int r = 0; r < 4; r++)
                s[t][r] = ((mloc >> ((t << 2) | r)) & 1u) ? 0.f : -1e20f;
#pragma unroll
        for (int t = 0; t < 4; t++) {
            int kc = (t << 4) + c16;
            int sw = (kc & 7) << 3;
            bf16x8 kf0 = *(const bf16x8*)&lds_k[buf][kc * 64 + ((8 * g) ^ sw)];
            bf16x8 kf1 = *(const bf16x8*)&lds_k[buf][kc * 64 + ((8 * g + 32) ^ sw)];
            s[t] = __builtin_amdgcn_mfma_f32_16x16x32_bf16(kf0, qa0, s[t], 0, 0, 0);
            s[t] = __builtin_amdgcn_mfma_f32_16x16x32_bf16(kf1, qa1, s[t], 0, 0, 0);
        }
        // per-lane row max over 16 values + cross-g reduce (2 shfl)
        float pmax = fmaxf(fmaxf(fmaxf(s[0][0], s[0][1]), fmaxf(s[0][2], s[0][3])),
                           fmaxf(fmaxf(s[1][0], s[1][1]), fmaxf(s[1][2], s[1][3])));
        pmax = fmaxf(pmax, fmaxf(fmaxf(fmaxf(s[2][0], s[2][1]), fmaxf(s[2][2], s[2][3])),
                                 fmaxf(fmaxf(s[3][0], s[3][1]), fmaxf(s[3][2], s[3][3]))));
        pmax = fmaxf(pmax, __shfl_xor(pmax, 16));
        pmax = fmaxf(pmax, __shfl_xor(pmax, 32));
        // defer-max (T13): rescale only when max grew past threshold (exp2 domain, THR=8)
        if (__ballot(pmax > m_r + 8.f)) {
            float mnew = fmaxf(m_r, pmax);
            float sc = exp2_hw(m_r - mnew);
            m_r = mnew;
            l_r *= sc;
#pragma unroll
            for (int dt = 0; dt < 4; dt++) o[dt] *= sc;
        }
        // P = exp2(S - m), pack to bf16 pairs
        float ladd = 0.f;
        u32 pk[4][2];
#pragma unroll
        for (int t = 0; t < 4; t++) {
            float p0 = exp2_hw(s[t][0] - m_r);
            float p1 = exp2_hw(s[t][1] - m_r);
            float p2 = exp2_hw(s[t][2] - m_r);
            float p3 = exp2_hw(s[t][3] - m_r);
            ladd += (p0 + p1) + (p2 + p3);
            pk[t][0] = cvtpk_bf16(p0, p1);
            pk[t][1] = cvtpk_bf16(p2, p3);
        }
        ladd += __shfl_xor(ladd, 16);
        ladd += __shfl_xor(ladd, 32);
        l_r += ladd;
        // P[q=c16][k] -> per-wave swizzled LDS (cross-g exchange), 4x ds_write_b64
        char* pbase = (char*)&lds_p[wave][0];
        int swp = (c16 & 7) << 4;
#pragma unroll
        for (int t = 0; t < 4; t++) {
            u64 w2 = ((u64)pk[t][1] << 32) | pk[t][0];
            *(u64*)(pbase + ((c16 * 128 + 32 * t + 8 * g) ^ swp)) = w2;
        }
        // PV (swapped): O^T[d][q=c16] += V^T-frag(A) x P-frag(B)
        bf16x8 pa0 = *(const bf16x8*)(pbase + ((c16 * 128 + 16 * g) ^ swp));
        bf16x8 pa1 = *(const bf16x8*)(pbase + ((c16 * 128 + 64 + 16 * g) ^ swp));
#pragma unroll
        for (int dt = 0; dt < 4; dt++) {
            int dr = (dt << 4) + c16;
            int swv = (dr & 7) << 3;
            bf16x8 vf0 = *(const bf16x8*)&lds_v[buf][dr * 64 + ((8 * g) ^ swv)];
            bf16x8 vf1 = *(const bf16x8*)&lds_v[buf][dr * 64 + ((8 * g + 32) ^ swv)];
            o[dt] = __builtin_amdgcn_mfma_f32_16x16x32_bf16(vf0, pa0, o[dt], 0, 0, 0);
            o[dt] = __builtin_amdgcn_mfma_f32_16x16x32_bf16(vf1, pa1, o[dt], 0, 0, 0);
        }
    };

    STAGE(0, 0);
    __syncthreads();
    for (int kt = 0; kt < SEQ / 64; kt++) {
        int buf = kt & 1;
        if (kt + 1 < SEQ / 64) STAGE(buf ^ 1, kt + 1);
        COMPUTE(buf, kt);
        __syncthreads();
    }

    // epilogue: out[q=c16][d=16dt+4g+r] = o/l  (4x 8B stores)
    float inv = 1.f / l_r;
    size_t obase = ((size_t)n * SEQ + qw + c16) * EMB + h * HD;
#pragma unroll
    for (int dt = 0; dt < 4; dt++) {
        u32 w0 = cvtpk_bf16(o[dt][0] * inv, o[dt][1] * inv);
        u32 w1 = cvtpk_bf16(o[dt][2] * inv, o[dt][3] * inv);
        u64 w2 = ((u64)w1 << 32) | w0;
        *(u64*)(ao + obase + (dt << 4) + (g << 2)) = w2;
    }
}

// ---------------- output projection: out[M=8192][1024] = A[M][1024] @ W[1024][1024]^T + b ----------------
__global__ __launch_bounds__(256, 2) void proj_k(
    const u16* __restrict__ a, const u16* __restrict__ w,
    const float* __restrict__ bias, float* __restrict__ out)
{
    __shared__ __align__(16) u16 lds_a[2][128 * 64];
    __shared__ __align__(16) u16 lds_b[2][128 * 64];
    const int tid = threadIdx.x;
    const int wave = tid >> 6, lane = tid & 63;
    const int g = lane >> 4, c16 = lane & 15;
    const int m0 = blockIdx.y << 7, n0 = blockIdx.x << 7;
    const int wm = wave >> 1, wn = wave & 1;
    f32x4 acc[4][4];
#pragma unroll
    for (int i = 0; i < 4; i++)
#pragma unroll
        for (int j = 0; j < 4; j++) acc[i][j] = (f32x4){0.f, 0.f, 0.f, 0.f};

    auto STAGE = [&](int buf, int k0) {
#pragma unroll
        for (int i = 0; i < 4; i++) {
            int off = (i << 8) + tid;
            int row = off >> 3;
            int sch = (off & 7) ^ (row & 7);
            int ldso = ((i << 8) + (wave << 6)) << 3;
            gld16(a + (size_t)(m0 + row) * EMB + k0 + (sch << 3), &lds_a[buf][ldso]);
            gld16(w + (size_t)(n0 + row) * EMB + k0 + (sch << 3), &lds_b[buf][ldso]);
        }
    };

    auto COMP = [&](int buf) {
#pragma unroll
        for (int c = 0; c < 2; c++) {
            bf16x8 af[4], bfr[4];
#pragma unroll
            for (int mt = 0; mt < 4; mt++) {
                int row = (wm << 6) + (mt << 4) + c16;
                af[mt] = *(const bf16x8*)&lds_a[buf][row * 64 + ((8 * g + 32 * c) ^ ((row & 7) << 3))];
            }
#pragma unroll
            for (int nt = 0; nt < 4; nt++) {
                int row = (wn << 6) + (nt << 4) + c16;
                bfr[nt] = *(const bf16x8*)&lds_b[buf][row * 64 + ((8 * g + 32 * c) ^ ((row & 7) << 3))];
            }
#pragma unroll
            for (int mt = 0; mt < 4; mt++)
#pragma unroll
                for (int nt = 0; nt < 4; nt++)
                    acc[mt][nt] = __builtin_amdgcn_mfma_f32_16x16x32_bf16(af[mt], bfr[nt], acc[mt][nt], 0, 0, 0);
        }
    };

    STAGE(0, 0);
    __syncthreads();
    for (int ki = 0; ki < EMB / 64; ki++) {
        int buf = ki & 1;
        if (ki + 1 < EMB / 64) STAGE(buf ^ 1, (ki + 1) << 6);
        COMP(buf);
        __syncthreads();
    }

#pragma unroll
    for (int nt = 0; nt < 4; nt++) {
        int col = n0 + (wn << 6) + (nt << 4) + c16;
        float bv = bias[col];
#pragma unroll
        for (int mt = 0; mt < 4; mt++) {
#pragma unroll
            for (int r = 0; r < 4; r++) {
                int row = m0 + (wm << 6) + (mt << 4) + 4 * g + r;
                out[(size_t)row * EMB + col] = acc[mt][nt][r] + bv;
            }
        }
    }
}

extern "C" void kernel_launch(void* const* d_in, const int* in_sizes, int n_in,
                              void* d_out, int out_size, void* d_ws, size_t ws_size,
                              hipStream_t stream) {
    const float* V = (const float*)d_in[0];
    const float* K = (const float*)d_in[1];
    const float* Q = (const float*)d_in[2];
    const int* M = (const int*)d_in[3];
    const float* W = (const float*)d_in[4];
    const float* B = (const float*)d_in[5];
    float* out = (float*)d_out;

    char* ws = (char*)d_ws;
    u16* qb = (u16*)(ws);                       // 16 MB  [n][h][s][d] bf16, pre-scaled log2e/32
    u16* kb = (u16*)(ws + ((size_t)16 << 20));  // 16 MB
    u16* vt = (u16*)(ws + ((size_t)32 << 20));  // 16 MB  [n][h][d][s]
    u64* mb = (u64*)(ws + ((size_t)48 << 20));  //  2 MB  permuted bitmask
    u16* wb = (u16*)(ws + ((size_t)50 << 20));  //  2 MB  W bf16
    u16* ao = (u16*)(ws + ((size_t)52 << 20));  // 16 MB  attn out bf16 [n][q][e]

    prep_qk<<<8192, 256, 0, stream>>>(Q, K, qb, kb);
    prep_v<<<dim3(SEQ / 64, NHD, NB), 256, 0, stream>>>(V, vt);
    prep_mask<<<1024, 256, 0, stream>>>(M, mb);
    prep_w<<<1024, 256, 0, stream>>>(W, wb);
    attn_k<<<2048, 256, 0, stream>>>(qb, kb, vt, mb, ao);
    proj_k<<<dim3(EMB / 128, (NB * SEQ) / 128), 256, 0, stream>>>(ao, wb, B, out);
}

// Round 6
// 349.428 us; speedup vs baseline: 1.3830x; 1.0780x over previous
//
#include <hip/hip_runtime.h>
#include <stdint.h>

#define SEQ 2048
#define NB 4
#define NHD 16
#define HD 64
#define EMB 1024

typedef unsigned short u16;
typedef unsigned int u32;
typedef unsigned long long u64;
typedef __bf16 bf16x8 __attribute__((ext_vector_type(8)));
typedef float f32x4 __attribute__((ext_vector_type(4)));
typedef float f32x16 __attribute__((ext_vector_type(16)));
typedef u32 u32x4 __attribute__((ext_vector_type(4)));

__device__ __forceinline__ u16 f2bf(float f) {
    u32 u = __builtin_bit_cast(u32, f);
    u32 r = u + 0x7FFFu + ((u >> 16) & 1u);   // RNE
    return (u16)(r >> 16);
}

__device__ __forceinline__ float exp2_hw(float x) {
    float r;
    asm("v_exp_f32 %0, %1" : "=v"(r) : "v"(x));
    return r;
}

__device__ __forceinline__ u32 cvtpk_bf16(float lo, float hi) {
    u32 r;
    asm("v_cvt_pk_bf16_f32 %0, %1, %2" : "=v"(r) : "v"(lo), "v"(hi));
    return r;
}

// swaps upper 32 lanes of a with lower 32 lanes of b (in place)
__device__ __forceinline__ void permswap(u32& a, u32& b) {
    asm volatile("v_permlane32_swap_b32 %0, %1" : "+v"(a), "+v"(b));
}

__device__ __forceinline__ void gld16(const void* g, void* l) {
    __builtin_amdgcn_global_load_lds(
        (const __attribute__((address_space(1))) u32*)g,
        (__attribute__((address_space(3))) u32*)l, 16, 0, 0);
}

// ---------------- prep: Q (scaled log2e/32) and K -> bf16 [n][h][s][d] ----------------
__global__ void prep_qk(const float* __restrict__ q, const float* __restrict__ k,
                        u16* __restrict__ qb, u16* __restrict__ kb) {
    int tid = blockIdx.x * 256 + threadIdx.x;   // N*S*H*16 threads
    int unit = tid >> 4;                        // (n,s,h)
    int dq = (tid & 15) << 2;
    int h = unit & (NHD - 1);
    int ns = unit >> 4;                         // n*S+s
    int n = ns >> 11, s = ns & (SEQ - 1);
    size_t src = (size_t)ns * EMB + h * HD + dq;
    float4 qv = *(const float4*)(q + src);
    float4 kv = *(const float4*)(k + src);
    size_t dst = ((size_t)(n * NHD + h) * SEQ + s) * HD + dq;
    const float QS = 0.04508422f;               // (1/32) * log2(e): S in exp2 domain
    ushort4 qo, ko;
    qo.x = f2bf(qv.x * QS); qo.y = f2bf(qv.y * QS);
    qo.z = f2bf(qv.z * QS); qo.w = f2bf(qv.w * QS);
    ko.x = f2bf(kv.x); ko.y = f2bf(kv.y); ko.z = f2bf(kv.z); ko.w = f2bf(kv.w);
    *(ushort4*)(qb + dst) = qo;
    *(ushort4*)(kb + dst) = ko;
}

// ---------------- prep: V -> bf16 transposed [n][h][d][s] ----------------
__global__ void prep_v(const float* __restrict__ v, u16* __restrict__ vt) {
    __shared__ float t[64][65];
    int s0 = blockIdx.x << 6, h = blockIdx.y, n = blockIdx.z;
    int tid = threadIdx.x;
    int c = (tid & 15) << 2;
    int r0 = tid >> 4;
#pragma unroll
    for (int it = 0; it < 4; it++) {
        int r = r0 + (it << 4);
        float4 val = *(const float4*)(v + ((size_t)n * SEQ + s0 + r) * EMB + h * HD + c);
        t[c][r] = val.x; t[c + 1][r] = val.y; t[c + 2][r] = val.z; t[c + 3][r] = val.w;
    }
    __syncthreads();
    int d = tid >> 2, so = (tid & 3) << 4;
    size_t dst = ((size_t)(n * NHD + h) * HD + d) * SEQ + s0 + so;
#pragma unroll
    for (int j = 0; j < 4; j++) {
        ushort4 o;
        o.x = f2bf(t[d][so + 4 * j + 0]); o.y = f2bf(t[d][so + 4 * j + 1]);
        o.z = f2bf(t[d][so + 4 * j + 2]); o.w = f2bf(t[d][so + 4 * j + 3]);
        *(ushort4*)(vt + dst + 4 * j) = o;
    }
}

// ---------------- prep: mask int32 -> permuted-bit u64 words via ballot ----------------
// 32x32 MFMA layout: bit j (j = 32s + 16h + 4rq + rl) holds element k = 32s + 8rq + 4h + rl
// -> attn lane (hi=h) reads its 16 bits for subtile s as one contiguous field, bit pos = reg.
__global__ void prep_mask(const int* __restrict__ m, u64* __restrict__ mb) {
    int gw = (blockIdx.x * 256 + threadIdx.x) >> 6;   // global wave id (4096 waves)
    int lane = threadIdx.x & 63;
    int src = (lane & 32) | ((lane & 12) << 1) | ((lane & 16) >> 2) | (lane & 3);
    for (int i = 0; i < 64; i++) {
        size_t widx = (size_t)gw * 64 + i;            // word index, N*S*32 total
        int v = m[widx * 64 + src];
        u64 b = __ballot(v != 0);
        if (lane == 0) mb[widx] = b;
    }
}

// ---------------- prep: W -> bf16 ----------------
__global__ void prep_w(const float* __restrict__ w, u16* __restrict__ wb) {
    int tid = blockIdx.x * 256 + threadIdx.x;
    float4 v = *(const float4*)(w + (size_t)tid * 4);
    ushort4 o;
    o.x = f2bf(v.x); o.y = f2bf(v.y); o.z = f2bf(v.z); o.w = f2bf(v.w);
    *(ushort4*)(wb + (size_t)tid * 4) = o;
}

// ---------------- flash attention: 32x32 swapped-operand, in-register P (T12) ----------------
// grid 1024 blocks (T1 chunked XCD swizzle), 4 waves x 32 q rows = 128 q/block. K-tile=64.
__global__ __launch_bounds__(256, 4) void attn_k(
    const u16* __restrict__ qb, const u16* __restrict__ kb,
    const u16* __restrict__ vt, const u64* __restrict__ mbits,
    u16* __restrict__ ao)
{
    __shared__ __align__(16) u16 lds_k[2][64 * 64];
    __shared__ __align__(16) u16 lds_v[2][64 * 64];
    const int tid = threadIdx.x;
    const int wave = tid >> 6, lane = tid & 63;
    const int l31 = lane & 31, hi = lane >> 5;
    // T1 chunked swizzle: 1024 blocks, 128/XCD contiguous
    const int bid = blockIdx.x;
    const int swz = (bid & 7) * 128 + (bid >> 3);
    const int n = swz >> 8, h = (swz >> 4) & 15, qt = swz & 15;
    const int qw = (qt << 7) + (wave << 5);
    const size_t nh = (size_t)(n * NHD + h);
    const u16* Qp = qb + nh * SEQ * HD;
    const u16* Kp = kb + nh * SEQ * HD;
    const u16* Vp = vt + nh * HD * SEQ;
    const u64* mrow = mbits + ((size_t)n * SEQ + qw + l31) * (SEQ / 64);

    // Q fragments (B-operand): col q = l31, k(d) = ds*16 + 8*hi + 0..7
    bf16x8 qa[4];
#pragma unroll
    for (int ds = 0; ds < 4; ds++)
        qa[ds] = *(const bf16x8*)(Qp + (size_t)(qw + l31) * HD + ds * 16 + 8 * hi);

    f32x16 o0 = {0.f}, o1 = {0.f};
#pragma unroll
    for (int r = 0; r < 16; r++) { o0[r] = 0.f; o1[r] = 0.f; }
    float m_r = -INFINITY, l_r = 0.f;

    auto STAGE = [&](int buf, int kt) {
        int k0 = kt << 6;
#pragma unroll
        for (int i = 0; i < 2; i++) {
            int off = (i << 8) + tid;                 // 16B-chunk index 0..511
            int row = off >> 3;
            int sch = (off & 7) ^ (row & 7);          // pre-swizzled source chunk
            int ldso = ((i << 8) + (wave << 6)) << 3; // wave-uniform LDS base (elems)
            gld16(Kp + (size_t)(k0 + row) * HD + (sch << 3), &lds_k[buf][ldso]);
            gld16(Vp + (size_t)row * SEQ + k0 + (sch << 3), &lds_v[buf][ldso]);
        }
    };

    auto COMPUTE = [&](int buf, int kt) {
        // mask as MFMA C-init: bit r of 16-bit field (s, hi) <-> acc reg r of subtile s
        u64 mw = mrow[kt];
        u32 ml0 = (u32)(mw >> (hi << 4)) & 0xFFFFu;
        u32 ml1 = (u32)(mw >> (32 + (hi << 4))) & 0xFFFFu;
        f32x16 s0, s1;
#pragma unroll
        for (int r = 0; r < 16; r++) {
            s0[r] = ((ml0 >> r) & 1u) ? 0.f : -1e20f;
            s1[r] = ((ml1 >> r) & 1u) ? 0.f : -1e20f;
        }
        // QK^T (swapped): S^T[k][q=l31] = K-frag(A) x Q-frag(B)
        const char* kbase = (const char*)&lds_k[buf][0];
#pragma unroll
        for (int ds = 0; ds < 4; ds++) {
            int c = ((ds << 1) + hi) ^ (l31 & 7);
            bf16x8 ka0 = *(const bf16x8*)(kbase + l31 * 128 + (c << 4));
            bf16x8 ka1 = *(const bf16x8*)(kbase + (l31 + 32) * 128 + (c << 4));
            s0 = __builtin_amdgcn_mfma_f32_32x32x16_bf16(ka0, qa[ds], s0, 0, 0, 0);
            s1 = __builtin_amdgcn_mfma_f32_32x32x16_bf16(ka1, qa[ds], s1, 0, 0, 0);
        }
        // row max: 31 in-lane + 1 cross-hi shuffle
        float pmax = fmaxf(s0[0], s0[1]);
#pragma unroll
        for (int r = 2; r < 16; r++) pmax = fmaxf(pmax, s0[r]);
#pragma unroll
        for (int r = 0; r < 16; r++) pmax = fmaxf(pmax, s1[r]);
        pmax = fmaxf(pmax, __shfl_xor(pmax, 32));
        // defer-max (T13): rescale only when max grew past threshold (exp2 domain, THR=8)
        if (__ballot(pmax > m_r + 8.f)) {
            float mnew = fmaxf(m_r, pmax);
            float sc = exp2_hw(m_r - mnew);
            m_r = mnew;
            l_r *= sc;
#pragma unroll
            for (int r = 0; r < 16; r++) { o0[r] *= sc; o1[r] *= sc; }
        }
        // P = exp2(S - m) in place; accumulate l
        float ladd = 0.f;
#pragma unroll
        for (int r = 0; r < 16; r++) { s0[r] = exp2_hw(s0[r] - m_r); ladd += s0[r]; }
#pragma unroll
        for (int r = 0; r < 16; r++) { s1[r] = exp2_hw(s1[r] - m_r); ladd += s1[r]; }
        l_r += ladd;  // cross-hi reduced once in epilogue
        // pack to bf16 + in-register redistribution (T12): after the swaps,
        // frag[ks] = (w[4ks..4ks+3]) is the PV B-operand for BOTH half-waves.
        u32 w[16];
#pragma unroll
        for (int i = 0; i < 8; i++) w[i] = cvtpk_bf16(s0[2 * i], s0[2 * i + 1]);
#pragma unroll
        for (int i = 0; i < 8; i++) w[8 + i] = cvtpk_bf16(s1[2 * i], s1[2 * i + 1]);
        permswap(w[0], w[2]);  permswap(w[1], w[3]);
        permswap(w[4], w[6]);  permswap(w[5], w[7]);
        permswap(w[8], w[10]); permswap(w[9], w[11]);
        permswap(w[12], w[14]); permswap(w[13], w[15]);
        // PV (swapped): O^T[d][q=l31] += V^T-frag(A) x P-frag(B), k-slices ks=0..3
        const char* vbase = (const char*)&lds_v[buf][0];
#pragma unroll
        for (int ks = 0; ks < 4; ks++) {
            u32x4 t = {w[4 * ks], w[4 * ks + 1], w[4 * ks + 2], w[4 * ks + 3]};
            bf16x8 pb = __builtin_bit_cast(bf16x8, t);
            int c = ((ks << 1) + hi) ^ (l31 & 7);
            bf16x8 va0 = *(const bf16x8*)(vbase + l31 * 128 + (c << 4));
            bf16x8 va1 = *(const bf16x8*)(vbase + (l31 + 32) * 128 + (c << 4));
            o0 = __builtin_amdgcn_mfma_f32_32x32x16_bf16(va0, pb, o0, 0, 0, 0);
            o1 = __builtin_amdgcn_mfma_f32_32x32x16_bf16(va1, pb, o1, 0, 0, 0);
        }
    };

    STAGE(0, 0);
    __syncthreads();
    for (int kt = 0; kt < SEQ / 64; kt++) {
        int buf = kt & 1;
        if (kt + 1 < SEQ / 64) STAGE(buf ^ 1, kt + 1);
        COMPUTE(buf, kt);
        __syncthreads();
    }

    // epilogue: cross-hi l reduce, then out[q=l31][d = dsub*32 + 8*rq + 4*hi + 0..3]
    l_r += __shfl_xor(l_r, 32);
    float inv = 1.f / l_r;
    size_t ob = ((size_t)n * SEQ + qw + l31) * EMB + h * HD;
#pragma unroll
    for (int rq = 0; rq < 4; rq++) {
        u32 a0 = cvtpk_bf16(o0[4 * rq] * inv, o0[4 * rq + 1] * inv);
        u32 b0 = cvtpk_bf16(o0[4 * rq + 2] * inv, o0[4 * rq + 3] * inv);
        *(u64*)(ao + ob + 8 * rq + 4 * hi) = ((u64)b0 << 32) | a0;
        u32 a1 = cvtpk_bf16(o1[4 * rq] * inv, o1[4 * rq + 1] * inv);
        u32 b1 = cvtpk_bf16(o1[4 * rq + 2] * inv, o1[4 * rq + 3] * inv);
        *(u64*)(ao + ob + 32 + 8 * rq + 4 * hi) = ((u64)b1 << 32) | a1;
    }
}

// ---------------- output projection: out[M=8192][1024] = A[M][1024] @ W[1024][1024]^T + b ----------------
__global__ __launch_bounds__(256, 2) void proj_k(
    const u16* __restrict__ a, const u16* __restrict__ w,
    const float* __restrict__ bias, float* __restrict__ out)
{
    __shared__ __align__(16) u16 lds_a[2][128 * 64];
    __shared__ __align__(16) u16 lds_b[2][128 * 64];
    const int tid = threadIdx.x;
    const int wave = tid >> 6, lane = tid & 63;
    const int g = lane >> 4, c16 = lane & 15;
    const int m0 = blockIdx.y << 7, n0 = blockIdx.x << 7;
    const int wm = wave >> 1, wn = wave & 1;
    f32x4 acc[4][4];
#pragma unroll
    for (int i = 0; i < 4; i++)
#pragma unroll
        for (int j = 0; j < 4; j++) acc[i][j] = (f32x4){0.f, 0.f, 0.f, 0.f};

    auto STAGE = [&](int buf, int k0) {
#pragma unroll
        for (int i = 0; i < 4; i++) {
            int off = (i << 8) + tid;
            int row = off >> 3;
            int sch = (off & 7) ^ (row & 7);
            int ldso = ((i << 8) + (wave << 6)) << 3;
            gld16(a + (size_t)(m0 + row) * EMB + k0 + (sch << 3), &lds_a[buf][ldso]);
            gld16(w + (size_t)(n0 + row) * EMB + k0 + (sch << 3), &lds_b[buf][ldso]);
        }
    };

    auto COMP = [&](int buf) {
#pragma unroll
        for (int c = 0; c < 2; c++) {
            bf16x8 af[4], bfr[4];
#pragma unroll
            for (int mt = 0; mt < 4; mt++) {
                int row = (wm << 6) + (mt << 4) + c16;
                af[mt] = *(const bf16x8*)&lds_a[buf][row * 64 + ((8 * g + 32 * c) ^ ((row & 7) << 3))];
            }
#pragma unroll
            for (int nt = 0; nt < 4; nt++) {
                int row = (wn << 6) + (nt << 4) + c16;
                bfr[nt] = *(const bf16x8*)&lds_b[buf][row * 64 + ((8 * g + 32 * c) ^ ((row & 7) << 3))];
            }
#pragma unroll
            for (int mt = 0; mt < 4; mt++)
#pragma unroll
                for (int nt = 0; nt < 4; nt++)
                    acc[mt][nt] = __builtin_amdgcn_mfma_f32_16x16x32_bf16(af[mt], bfr[nt], acc[mt][nt], 0, 0, 0);
        }
    };

    STAGE(0, 0);
    __syncthreads();
    for (int ki = 0; ki < EMB / 64; ki++) {
        int buf = ki & 1;
        if (ki + 1 < EMB / 64) STAGE(buf ^ 1, (ki + 1) << 6);
        COMP(buf);
        __syncthreads();
    }

#pragma unroll
    for (int nt = 0; nt < 4; nt++) {
        int col = n0 + (wn << 6) + (nt << 4) + c16;
        float bv = bias[col];
#pragma unroll
        for (int mt = 0; mt < 4; mt++) {
#pragma unroll
            for (int r = 0; r < 4; r++) {
                int row = m0 + (wm << 6) + (mt << 4) + 4 * g + r;
                out[(size_t)row * EMB + col] = acc[mt][nt][r] + bv;
            }
        }
    }
}

extern "C" void kernel_launch(void* const* d_in, const int* in_sizes, int n_in,
                              void* d_out, int out_size, void* d_ws, size_t ws_size,
                              hipStream_t stream) {
    const float* V = (const float*)d_in[0];
    const float* K = (const float*)d_in[1];
    const float* Q = (const float*)d_in[2];
    const int* M = (const int*)d_in[3];
    const float* W = (const float*)d_in[4];
    const float* B = (const float*)d_in[5];
    float* out = (float*)d_out;

    char* ws = (char*)d_ws;
    u16* qb = (u16*)(ws);                       // 16 MB  [n][h][s][d] bf16, pre-scaled log2e/32
    u16* kb = (u16*)(ws + ((size_t)16 << 20));  // 16 MB
    u16* vt = (u16*)(ws + ((size_t)32 << 20));  // 16 MB  [n][h][d][s]
    u64* mb = (u64*)(ws + ((size_t)48 << 20));  //  2 MB  permuted bitmask (32x32 layout)
    u16* wb = (u16*)(ws + ((size_t)50 << 20));  //  2 MB  W bf16
    u16* ao = (u16*)(ws + ((size_t)52 << 20));  // 16 MB  attn out bf16 [n][q][e]

    prep_qk<<<8192, 256, 0, stream>>>(Q, K, qb, kb);
    prep_v<<<dim3(SEQ / 64, NHD, NB), 256, 0, stream>>>(V, vt);
    prep_mask<<<1024, 256, 0, stream>>>(M, mb);
    prep_w<<<1024, 256, 0, stream>>>(W, wb);
    attn_k<<<1024, 256, 0, stream>>>(qb, kb, vt, mb, ao);
    proj_k<<<dim3(EMB / 128, (NB * SEQ) / 128), 256, 0, stream>>>(ao, wb, B, out);
}